// Round 3
// baseline (211.533 us; speedup 1.0000x reference)
//
#include <hip/hip_runtime.h>
#include <math.h>

#define NPTS 16384
#define NSMP 8192          // 8 * 1024
#define KNN 10
#define QPB 4              // queries per block (shared by all waves)
#define SPLIT 4            // waves per block = point-range splits
#define PPW (NPTS / SPLIT) // 4096 points per wave
#define ITERS (PPW / 64)   // 64 iterations of 64 candidates

// order-preserving float<->uint bijection (for atomicMin on possibly-negative d')
__device__ __forceinline__ unsigned mapf(float f) {
    unsigned u = __float_as_uint(f);
    return (u & 0x80000000u) ? ~u : (u | 0x80000000u);
}
__device__ __forceinline__ float unmapf(unsigned k) {
    unsigned u = (k & 0x80000000u) ? (k ^ 0x80000000u) : ~k;
    return __uint_as_float(u);
}

// pack xyz -> (x, y, z, |p|^2) float4, one thread per 4 points
__global__ __launch_bounds__(256) void pack_kernel(const float* __restrict__ xyz,
                                                   float4* __restrict__ pk) {
    const int t = blockIdx.x * 256 + threadIdx.x;        // 32768 threads
    const float4* src = (const float4*)xyz;
    const float4 a = src[t * 3 + 0];
    const float4 b = src[t * 3 + 1];
    const float4 c = src[t * 3 + 2];
    pk[t * 4 + 0] = make_float4(a.x, a.y, a.z, fmaf(a.x, a.x, fmaf(a.y, a.y, a.z * a.z)));
    pk[t * 4 + 1] = make_float4(a.w, b.x, b.y, fmaf(a.w, a.w, fmaf(b.x, b.x, b.y * b.y)));
    pk[t * 4 + 2] = make_float4(b.z, b.w, c.x, fmaf(b.z, b.z, fmaf(b.w, b.w, c.x * c.x)));
    pk[t * 4 + 3] = make_float4(c.y, c.z, c.w, fmaf(c.y, c.y, fmaf(c.z, c.z, c.w * c.w)));
}

__global__ __launch_bounds__(256, 8) void knn_kernel(
    const float4* __restrict__ pk,
    const float* __restrict__ xyz,
    const float* __restrict__ sxyz,
    const float* __restrict__ temp,
    float* __restrict__ out)
{
    __shared__ unsigned shTh[QPB];                 // shared prune thresholds (mapped)
    __shared__ float candD[QPB][SPLIT * KNN];
    __shared__ int   candI[QPB][SPLIT * KNN];

    const int lane  = threadIdx.x & 63;
    const int w     = threadIdx.x >> 6;            // wave id = point split id
    const int qbase = blockIdx.x * QPB;
    const int b     = qbase >> 10;                 // batch

    if (threadIdx.x < QPB) shTh[threadIdx.x] = 0xFF800000u;   // map(+INF)
    __syncthreads();

    // queries, premultiplied by -2 for d' = |p|^2 - 2 p.q
    float nqx[QPB], nqy[QPB], nqz[QPB];
    #pragma unroll
    for (int q = 0; q < QPB; ++q) {
        const float* s = sxyz + (size_t)(qbase + q) * 3;
        nqx[q] = -2.f * s[0]; nqy[q] = -2.f * s[1]; nqz[q] = -2.f * s[2];
    }

    // wave-cooperative sorted partial top-K: lane j<10 holds j-th smallest (d', idx)
    float kd[QPB]; int ki[QPB]; float th[QPB];
    #pragma unroll
    for (int q = 0; q < QPB; ++q) { kd[q] = INFINITY; ki[q] = 0; th[q] = INFINITY; }

    const float4* pw = pk + (size_t)b * NPTS + w * PPW + lane;
    int pidx = w * PPW + lane;                     // batch-local point index

    #pragma unroll 2
    for (int j = 0; j < ITERS; ++j, pw += 64, pidx += 64) {
        const float4 pv = *pw;                     // coalesced dwordx4, L2-resident
        if ((j & 3) == 0) {                        // periodic threshold refresh (stale-safe)
            #pragma unroll
            for (int q = 0; q < QPB; ++q)
                th[q] = fminf(th[q], unmapf(((volatile unsigned*)shTh)[q]));
        }
        float d[QPB];
        #pragma unroll
        for (int q = 0; q < QPB; ++q)
            d[q] = fmaf(pv.x, nqx[q], fmaf(pv.y, nqy[q], fmaf(pv.z, nqz[q], pv.w)));

        const float e = fminf(fminf(d[0] - th[0], d[1] - th[1]),
                              fminf(d[2] - th[2], d[3] - th[3]));
        if (__ballot(e < 0.f)) {                   // any candidate under any threshold?
            #pragma unroll
            for (int q = 0; q < QPB; ++q) {
                unsigned long long m = __ballot(d[q] < th[q]);
                while (m) {
                    const int srcl = __builtin_ctzll(m);
                    m &= m - 1;
                    const float v  = __shfl(d[q], srcl);
                    const int   vi = __shfl(pidx, srcl);
                    if (v < th[q]) {               // re-check vs tightened threshold
                        const int pos = __popcll(__ballot(kd[q] < v));
                        const float ud = __shfl_up(kd[q], 1);
                        const int   ui = __shfl_up(ki[q], 1);
                        if (lane < KNN && lane >= pos) {
                            kd[q] = (lane == pos) ? v  : ud;
                            ki[q] = (lane == pos) ? vi : ui;
                        }
                        const float newOwn = __shfl(kd[q], KNN - 1);
                        th[q] = fminf(th[q], newOwn);
                        if (lane == 0) atomicMin(&shTh[q], mapf(newOwn));
                    }
                }
            }
        }
    }

    // publish partials
    if (lane < KNN) {
        #pragma unroll
        for (int q = 0; q < QPB; ++q) {
            candD[q][w * KNN + lane] = kd[q];
            candI[q][w * KNN + lane] = ki[q];
        }
    }
    __syncthreads();

    // wave w merges query w: 40 candidates -> top 10 -> softmax -> weighted sum
    {
        const int q   = w;                          // QPB == SPLIT
        const int gid = qbase + q;
        const int M   = SPLIT * KNN;                // 40
        const float dv = (lane < M) ? candD[q][lane] : INFINITY;
        const int   iv = (lane < M) ? candI[q][lane] : 0x7FFFFFFF;
        int rank = 0;
        for (int k = 0; k < M; ++k) {
            const float dk = __shfl(dv, k);
            const int   ik = __shfl(iv, k);
            rank += ((dk < dv) || (dk == dv && ik < iv)) ? 1 : 0;
        }
        const float* s = sxyz + (size_t)gid * 3;
        const float q2 = fmaf(s[0], s[0], fmaf(s[1], s[1], s[2] * s[2]));
        const float d2 = fmaxf(dv + q2, 0.f);       // clamp matches reference
        float dm = d2;
        #pragma unroll
        for (int off = 32; off >= 1; off >>= 1) dm = fminf(dm, __shfl_xor(dm, off));
        const float t = temp[0];
        const float invt2 = 1.0f / (t * t);
        const bool sel = (lane < M) && (rank < KNN);
        const float wgt = sel ? __expf((dm - d2) * invt2) : 0.f;
        float px = 0.f, py = 0.f, pz = 0.f;
        if (sel) {
            const float* pp = xyz + ((size_t)b * NPTS + iv) * 3;
            px = pp[0]; py = pp[1]; pz = pp[2];
        }
        float sw = wgt, sx = wgt * px, sy = wgt * py, sz = wgt * pz;
        #pragma unroll
        for (int off = 32; off >= 1; off >>= 1) {
            sw += __shfl_xor(sw, off);
            sx += __shfl_xor(sx, off);
            sy += __shfl_xor(sy, off);
            sz += __shfl_xor(sz, off);
        }
        if (lane == 0) {
            const float inv = 1.0f / sw;
            out[(size_t)gid * 3 + 0] = sx * inv;
            out[(size_t)gid * 3 + 1] = sy * inv;
            out[(size_t)gid * 3 + 2] = sz * inv;
            if (gid == 0) out[NSMP * 3] = t;        // tuple output 2: temp
        }
    }
}

extern "C" void kernel_launch(void* const* d_in, const int* in_sizes, int n_in,
                              void* d_out, int out_size, void* d_ws, size_t ws_size,
                              hipStream_t stream) {
    const float* xyz  = (const float*)d_in[0];   // [8,16384,3]
    const float* sxyz = (const float*)d_in[1];   // [8,1024,3]
    const float* temp = (const float*)d_in[2];   // scalar
    float* out = (float*)d_out;

    float4* pk = (float4*)d_ws;                  // 131072 * 16 B = 2 MiB scratch

    hipLaunchKernelGGL(pack_kernel, dim3(128), dim3(256), 0, stream, xyz, pk);
    hipLaunchKernelGGL(knn_kernel, dim3(NSMP / QPB), dim3(256), 0, stream,
                       pk, xyz, sxyz, temp, out);
}

// Round 4
// 129.034 us; speedup vs baseline: 1.6394x; 1.6394x over previous
//
#include <hip/hip_runtime.h>
#include <math.h>

#define NPTS 16384
#define NSMP 8192          // 8 * 1024
#define KNN 10
#define QPB 4              // queries per block (shared by both waves)
#define SPLIT 2            // waves per block = point-range splits
#define PPW (NPTS / SPLIT) // 8192 points per wave
#define ITERS (PPW / 64)   // 128 iterations of 64 candidates

// pack xyz -> (x, y, z, |p|^2) float4, one thread per 4 points
__global__ __launch_bounds__(256) void pack_kernel(const float* __restrict__ xyz,
                                                   float4* __restrict__ pk) {
    const int t = blockIdx.x * 256 + threadIdx.x;        // 32768 threads
    const float4* src = (const float4*)xyz;
    const float4 a = src[t * 3 + 0];
    const float4 b = src[t * 3 + 1];
    const float4 c = src[t * 3 + 2];
    pk[t * 4 + 0] = make_float4(a.x, a.y, a.z, fmaf(a.x, a.x, fmaf(a.y, a.y, a.z * a.z)));
    pk[t * 4 + 1] = make_float4(a.w, b.x, b.y, fmaf(a.w, a.w, fmaf(b.x, b.x, b.y * b.y)));
    pk[t * 4 + 2] = make_float4(b.z, b.w, c.x, fmaf(b.z, b.z, fmaf(b.w, b.w, c.x * c.x)));
    pk[t * 4 + 3] = make_float4(c.y, c.z, c.w, fmaf(c.y, c.y, fmaf(c.z, c.z, c.w * c.w)));
}

__global__ __launch_bounds__(128) void knn_kernel(
    const float4* __restrict__ pk,
    const float* __restrict__ xyz,
    const float* __restrict__ sxyz,
    const float* __restrict__ temp,
    float* __restrict__ out)
{
    __shared__ float candD[QPB][SPLIT * KNN];      // 4 x 20
    __shared__ int   candI[QPB][SPLIT * KNN];

    const int lane  = threadIdx.x & 63;
    const int w     = threadIdx.x >> 6;            // wave id = point split id (0/1)
    const int qbase = blockIdx.x * QPB;
    const int b     = qbase >> 10;                 // batch

    // queries, premultiplied by -2 for d' = |p|^2 - 2 p.q
    float nqx[QPB], nqy[QPB], nqz[QPB];
    #pragma unroll
    for (int q = 0; q < QPB; ++q) {
        const float* s = sxyz + (size_t)(qbase + q) * 3;
        nqx[q] = -2.f * s[0]; nqy[q] = -2.f * s[1]; nqz[q] = -2.f * s[2];
    }

    // wave-cooperative sorted partial top-K: lane j<10 holds j-th smallest (d', idx)
    float kd[QPB]; int ki[QPB]; float th[QPB];
    #pragma unroll
    for (int q = 0; q < QPB; ++q) { kd[q] = INFINITY; ki[q] = 0; th[q] = INFINITY; }

    const float4* pw = pk + (size_t)b * NPTS + w * PPW + lane;
    int pidx = w * PPW + lane;                     // batch-local point index

    #pragma unroll 4
    for (int j = 0; j < ITERS; ++j, pw += 64, pidx += 64) {
        const float4 pv = *pw;                     // coalesced dwordx4, L2-resident
        float d[QPB];
        #pragma unroll
        for (int q = 0; q < QPB; ++q)
            d[q] = fmaf(pv.x, nqx[q], fmaf(pv.y, nqy[q], fmaf(pv.z, nqz[q], pv.w)));

        #pragma unroll
        for (int q = 0; q < QPB; ++q) {
            unsigned long long m = __ballot(d[q] < th[q]);
            while (m) {                            // rare after warm-up
                const int srcl = __builtin_ctzll(m);
                m &= m - 1;
                const float v  = __shfl(d[q], srcl);
                const int   vi = __shfl(pidx, srcl);
                if (v < th[q]) {                   // re-check vs tightened threshold
                    const int pos = __popcll(__ballot(kd[q] < v));
                    const float ud = __shfl_up(kd[q], 1);
                    const int   ui = __shfl_up(ki[q], 1);
                    if (lane < KNN && lane >= pos) {
                        kd[q] = (lane == pos) ? v  : ud;
                        ki[q] = (lane == pos) ? vi : ui;
                    }
                    th[q] = __shfl(kd[q], KNN - 1);
                }
            }
        }
    }

    // publish partials
    if (lane < KNN) {
        #pragma unroll
        for (int q = 0; q < QPB; ++q) {
            candD[q][w * KNN + lane] = kd[q];
            candI[q][w * KNN + lane] = ki[q];
        }
    }
    __syncthreads();

    // each wave merges 2 queries: 20 candidates -> top 10 -> softmax -> weighted sum
    const float t = temp[0];
    const float invt2 = 1.0f / (t * t);
    #pragma unroll
    for (int qq = 0; qq < QPB / SPLIT; ++qq) {
        const int q   = w * (QPB / SPLIT) + qq;
        const int gid = qbase + q;
        const int M   = SPLIT * KNN;                // 20
        const float dv = (lane < M) ? candD[q][lane] : INFINITY;
        const int   iv = (lane < M) ? candI[q][lane] : 0x7FFFFFFF;
        int rank = 0;
        #pragma unroll
        for (int k = 0; k < M; ++k) {
            const float dk = __shfl(dv, k);
            const int   ik = __shfl(iv, k);
            rank += ((dk < dv) || (dk == dv && ik < iv)) ? 1 : 0;
        }
        const float* s = sxyz + (size_t)gid * 3;
        const float q2 = fmaf(s[0], s[0], fmaf(s[1], s[1], s[2] * s[2]));
        const float d2 = fmaxf(dv + q2, 0.f);       // clamp matches reference
        float dm = d2;
        #pragma unroll
        for (int off = 32; off >= 1; off >>= 1) dm = fminf(dm, __shfl_xor(dm, off));
        const bool sel = (lane < M) && (rank < KNN);
        const float wgt = sel ? __expf((dm - d2) * invt2) : 0.f;
        float px = 0.f, py = 0.f, pz = 0.f;
        if (sel) {
            const float* pp = xyz + ((size_t)b * NPTS + iv) * 3;
            px = pp[0]; py = pp[1]; pz = pp[2];
        }
        float sw = wgt, sx = wgt * px, sy = wgt * py, sz = wgt * pz;
        #pragma unroll
        for (int off = 32; off >= 1; off >>= 1) {
            sw += __shfl_xor(sw, off);
            sx += __shfl_xor(sx, off);
            sy += __shfl_xor(sy, off);
            sz += __shfl_xor(sz, off);
        }
        if (lane == 0) {
            const float inv = 1.0f / sw;
            out[(size_t)gid * 3 + 0] = sx * inv;
            out[(size_t)gid * 3 + 1] = sy * inv;
            out[(size_t)gid * 3 + 2] = sz * inv;
            if (gid == 0) out[NSMP * 3] = t;        // tuple output 2: temp
        }
    }
}

extern "C" void kernel_launch(void* const* d_in, const int* in_sizes, int n_in,
                              void* d_out, int out_size, void* d_ws, size_t ws_size,
                              hipStream_t stream) {
    const float* xyz  = (const float*)d_in[0];   // [8,16384,3]
    const float* sxyz = (const float*)d_in[1];   // [8,1024,3]
    const float* temp = (const float*)d_in[2];   // scalar
    float* out = (float*)d_out;

    float4* pk = (float4*)d_ws;                  // 131072 * 16 B = 2 MiB scratch

    hipLaunchKernelGGL(pack_kernel, dim3(128), dim3(256), 0, stream, xyz, pk);
    hipLaunchKernelGGL(knn_kernel, dim3(NSMP / QPB), dim3(128), 0, stream,
                       pk, xyz, sxyz, temp, out);
}

// Round 5
// 62.799 us; speedup vs baseline: 3.3684x; 2.0547x over previous
//
#include <hip/hip_runtime.h>
#include <math.h>

#define NPTS 16384
#define NSMP 8192          // 8 * 1024
#define KNN 10
#define QPB 4              // queries per block (shared by all waves)
#define WAVES 4            // waves per block = point-range splits
#define PPW (NPTS / WAVES) // 4096 points per wave
#define ITERS (PPW / 64)   // 64 iterations of 64 candidates
#define CAP 256            // candidate buffer capacity per query

// order-preserving float -> uint bijection
__device__ __forceinline__ unsigned mapf(float f) {
    unsigned u = __float_as_uint(f);
    return (u & 0x80000000u) ? ~u : (u | 0x80000000u);
}
__device__ __forceinline__ float unmapf(unsigned k) {
    unsigned u = (k & 0x80000000u) ? (k ^ 0x80000000u) : ~k;
    return __uint_as_float(u);
}

// pack xyz -> (x, y, z, |p|^2) float4, one thread per 4 points
__global__ __launch_bounds__(256) void pack_kernel(const float* __restrict__ xyz,
                                                   float4* __restrict__ pk) {
    const int t = blockIdx.x * 256 + threadIdx.x;        // 32768 threads
    const float4* src = (const float4*)xyz;
    const float4 a = src[t * 3 + 0];
    const float4 b = src[t * 3 + 1];
    const float4 c = src[t * 3 + 2];
    pk[t * 4 + 0] = make_float4(a.x, a.y, a.z, fmaf(a.x, a.x, fmaf(a.y, a.y, a.z * a.z)));
    pk[t * 4 + 1] = make_float4(a.w, b.x, b.y, fmaf(a.w, a.w, fmaf(b.x, b.x, b.y * b.y)));
    pk[t * 4 + 2] = make_float4(b.z, b.w, c.x, fmaf(b.z, b.z, fmaf(b.w, b.w, c.x * c.x)));
    pk[t * 4 + 3] = make_float4(c.y, c.z, c.w, fmaf(c.y, c.y, fmaf(c.z, c.z, c.w * c.w)));
}

__global__ __launch_bounds__(256) void knn_kernel(
    const float4* __restrict__ pk,
    const float* __restrict__ xyz,
    const float* __restrict__ sxyz,
    const float* __restrict__ temp,
    float* __restrict__ out)
{
    __shared__ float minBuf[QPB][WAVES * 64];   // 4 KB: per-(lane,wave) minima
    __shared__ float tauS[QPB];
    __shared__ int   cnt[QPB];
    __shared__ float candD[QPB][CAP];           // 4 KB
    __shared__ int   candI[QPB][CAP];           // 4 KB

    const int lane  = threadIdx.x & 63;
    const int w     = threadIdx.x >> 6;         // wave id = point split id
    const int qbase = blockIdx.x * QPB;
    const int b     = qbase >> 10;              // batch

    if (threadIdx.x < QPB) cnt[threadIdx.x] = 0;

    // queries, premultiplied by -2 for d' = |p|^2 - 2 p.q
    float nqx[QPB], nqy[QPB], nqz[QPB];
    #pragma unroll
    for (int q = 0; q < QPB; ++q) {
        const float* s = sxyz + (size_t)(qbase + q) * 3;
        nqx[q] = -2.f * s[0]; nqy[q] = -2.f * s[1]; nqz[q] = -2.f * s[2];
    }

    const float4* pw = pk + (size_t)b * NPTS + (size_t)w * PPW + lane;

    // ---------------- pass A: branchless per-lane running min ----------------
    float mn[QPB];
    #pragma unroll
    for (int q = 0; q < QPB; ++q) mn[q] = INFINITY;

    #pragma unroll 4
    for (int j = 0; j < ITERS; ++j) {
        const float4 pv = pw[j * 64];           // coalesced dwordx4, L2-resident
        #pragma unroll
        for (int q = 0; q < QPB; ++q) {
            const float d = fmaf(pv.x, nqx[q], fmaf(pv.y, nqy[q], fmaf(pv.z, nqz[q], pv.w)));
            mn[q] = fminf(mn[q], d);
        }
    }
    #pragma unroll
    for (int q = 0; q < QPB; ++q) minBuf[q][w * 64 + lane] = mn[q];
    __syncthreads();

    // ------- threshold: wave w extracts 10th smallest of 256 minima (query w) -------
    {
        float r0 = minBuf[w][lane      ];
        float r1 = minBuf[w][lane +  64];
        float r2 = minBuf[w][lane + 128];
        float r3 = minBuf[w][lane + 192];
        float g = INFINITY;
        for (int k = 0; k < KNN; ++k) {
            const float v = fminf(fminf(r0, r1), fminf(r2, r3));
            g = v;
            #pragma unroll
            for (int off = 32; off >= 1; off >>= 1) g = fminf(g, __shfl_xor(g, off));
            const unsigned long long mm = __ballot(v == g);
            if (lane == (int)__builtin_ctzll(mm)) {   // remove one instance
                if      (r0 == g) r0 = INFINITY;
                else if (r1 == g) r1 = INFINITY;
                else if (r2 == g) r2 = INFINITY;
                else              r3 = INFINITY;
            }
        }
        if (lane == 0) tauS[w] = g;   // g = 10th smallest sub-min >= d10 (provable)
    }
    __syncthreads();

    float tau[QPB];
    #pragma unroll
    for (int q = 0; q < QPB; ++q) tau[q] = tauS[q];

    // ---------------- pass B: filter d <= tau, parallel compaction ----------------
    #pragma unroll 2
    for (int j = 0; j < ITERS; ++j) {
        const float4 pv = pw[j * 64];
        float d[QPB];
        #pragma unroll
        for (int q = 0; q < QPB; ++q)
            d[q] = fmaf(pv.x, nqx[q], fmaf(pv.y, nqy[q], fmaf(pv.z, nqz[q], pv.w)));

        const float e = fminf(fminf(d[0] - tau[0], d[1] - tau[1]),
                              fminf(d[2] - tau[2], d[3] - tau[3]));
        if (__ballot(e <= 0.f)) {               // ~6% of iterations
            const int pidx = w * PPW + j * 64 + lane;
            #pragma unroll
            for (int q = 0; q < QPB; ++q) {
                const unsigned long long mm = __ballot(d[q] <= tau[q]);
                if (mm) {
                    const int leader = (int)__builtin_ctzll(mm);
                    int base = 0;
                    if (lane == leader) base = atomicAdd(&cnt[q], __popcll(mm));
                    base = __shfl(base, leader);
                    if (d[q] <= tau[q]) {
                        const int slot = base + __popcll(mm & ((1ull << lane) - 1ull));
                        if (slot < CAP) { candD[q][slot] = d[q]; candI[q][slot] = pidx; }
                    }
                }
            }
        }
    }
    __syncthreads();

    // ------- final: wave w selects top-10 of query w's candidates (canonical) -------
    {
        const int q   = w;
        const int gid = qbase + q;
        const int c   = min(cnt[q], CAP);       // c >= 10 guaranteed

        unsigned long long k0 = (lane       < c) ? ((unsigned long long)mapf(candD[q][lane      ]) << 32) | (unsigned)candI[q][lane      ] : ~0ull;
        unsigned long long k1 = (lane +  64 < c) ? ((unsigned long long)mapf(candD[q][lane +  64]) << 32) | (unsigned)candI[q][lane +  64] : ~0ull;
        unsigned long long k2 = (lane + 128 < c) ? ((unsigned long long)mapf(candD[q][lane + 128]) << 32) | (unsigned)candI[q][lane + 128] : ~0ull;
        unsigned long long k3 = (lane + 192 < c) ? ((unsigned long long)mapf(candD[q][lane + 192]) << 32) | (unsigned)candI[q][lane + 192] : ~0ull;

        unsigned long long sel = ~0ull;
        for (int k = 0; k < KNN; ++k) {
            const unsigned long long a01 = (k0 < k1) ? k0 : k1;
            const unsigned long long a23 = (k2 < k3) ? k2 : k3;
            const unsigned long long v   = (a01 < a23) ? a01 : a23;
            unsigned long long g = v;
            #pragma unroll
            for (int off = 32; off >= 1; off >>= 1) {
                const unsigned long long o = __shfl_xor(g, off);
                g = (o < g) ? o : g;
            }
            if (lane == k) sel = g;             // lane k holds k-th smallest (sorted)
            const unsigned long long mm = __ballot(v == g);
            if (lane == (int)__builtin_ctzll(mm)) {
                if      (k0 == g) k0 = ~0ull;
                else if (k1 == g) k1 = ~0ull;
                else if (k2 == g) k2 = ~0ull;
                else              k3 = ~0ull;
            }
        }

        // epilogue: d2 = max(d' + |q|^2, 0), softmax over 10, weighted coord sum
        const float* s = sxyz + (size_t)gid * 3;
        const float q2 = fmaf(s[0], s[0], fmaf(s[1], s[1], s[2] * s[2]));
        const float dp = unmapf((unsigned)(sel >> 32));
        const float d2 = fmaxf(dp + q2, 0.f);
        const float dmin = __shfl(d2, 0);       // lane 0 = smallest (sorted order)
        const float t = temp[0];
        const float invt2 = 1.0f / (t * t);
        float wgt = 0.f, px = 0.f, py = 0.f, pz = 0.f;
        if (lane < KNN) {
            wgt = __expf((dmin - d2) * invt2);
            const int idx = (int)(unsigned)(sel & 0xFFFFFFFFull);
            const float* pp = xyz + ((size_t)b * NPTS + idx) * 3;
            px = pp[0]; py = pp[1]; pz = pp[2];
        }
        float sw = wgt, sx = wgt * px, sy = wgt * py, sz = wgt * pz;
        #pragma unroll
        for (int off = 8; off >= 1; off >>= 1) {
            sw += __shfl_xor(sw, off);
            sx += __shfl_xor(sx, off);
            sy += __shfl_xor(sy, off);
            sz += __shfl_xor(sz, off);
        }
        if (lane == 0) {
            const float inv = 1.0f / sw;
            out[(size_t)gid * 3 + 0] = sx * inv;
            out[(size_t)gid * 3 + 1] = sy * inv;
            out[(size_t)gid * 3 + 2] = sz * inv;
            if (gid == 0) out[NSMP * 3] = t;    // tuple output 2: temp
        }
    }
}

extern "C" void kernel_launch(void* const* d_in, const int* in_sizes, int n_in,
                              void* d_out, int out_size, void* d_ws, size_t ws_size,
                              hipStream_t stream) {
    const float* xyz  = (const float*)d_in[0];   // [8,16384,3]
    const float* sxyz = (const float*)d_in[1];   // [8,1024,3]
    const float* temp = (const float*)d_in[2];   // scalar
    float* out = (float*)d_out;

    float4* pk = (float4*)d_ws;                  // 131072 * 16 B = 2 MiB scratch

    hipLaunchKernelGGL(pack_kernel, dim3(128), dim3(256), 0, stream, xyz, pk);
    hipLaunchKernelGGL(knn_kernel, dim3(NSMP / QPB), dim3(256), 0, stream,
                       pk, xyz, sxyz, temp, out);
}